// Round 1
// baseline (484.503 us; speedup 1.0000x reference)
//
#include <hip/hip_runtime.h>
#include <hip/hip_bf16.h>

#define JN   17
#define DIM  512
#define HID  1024
#define MTOT 7776      // B*T = 32*243
#define BM   128
#define BN   256
#define BK   32
#define NTHR 512

typedef __attribute__((ext_vector_type(8))) short s16x8;
typedef __attribute__((ext_vector_type(4))) float f32x4;

// LDS layout (bytes)
#define A_OFF 0         // [128][512] bf16, 16B-unit swizzled (unit ^ (row&7))   : 131072
#define B_OFF 131072    // [256][32]  bf16, 16B-unit swizzled (unit ^ ((n>>1)&3)): 16384
#define Y_OFF 147456    // [4][128][3] f32 per-wn partials                        : 6144
#define SMEM_BYTES 153600

__device__ __forceinline__ unsigned int f2bf(float f) {
    return (unsigned int)__builtin_bit_cast(unsigned short, __float2bfloat16(f));
}

// exact-erf GELU via Abramowitz-Stegun 7.1.26 (|err| < 1.5e-7)
__device__ __forceinline__ float gelu_erf(float h) {
    float ah = fabsf(h);
    float z  = ah * 0.7071067811865476f;
    float t  = __builtin_amdgcn_rcpf(fmaf(0.3275911f, z, 1.0f));
    float p  = fmaf(fmaf(fmaf(fmaf(1.061405429f, t, -1.453152027f), t,
                              1.421413741f), t, -0.284496736f), t, 0.254829592f);
    float er = 1.0f - p * t * __expf(-z * z);   // erf(|z|) in [0,1)
    return fmaf(0.5f * ah, er, 0.5f * h);       // 0.5h(1+sgn(h)erf(|z|))
}

__global__ __launch_bounds__(NTHR, 2)
void pjh_fused(const float* __restrict__ x,
               const float* __restrict__ gamma,
               const float* __restrict__ beta,
               const float* __restrict__ w1,
               const float* __restrict__ b1,
               const float* __restrict__ w2,
               const float* __restrict__ b2,
               float* __restrict__ out)
{
    extern __shared__ char smem[];
    const int tid  = threadIdx.x;
    const int lane = tid & 63;
    const int wv   = tid >> 6;   // wave 0..7
    const int wm   = wv >> 2;    // 0..1 : rows 64*wm
    const int wn   = wv & 3;     // 0..3 : cols 64*wn (within BN)
    const int mt   = blockIdx.x; // 0..60
    const int j    = blockIdx.y; // 0..16

    // B-staging mapping: thread covers k-octet kb=8*t2 and n-pair n2
    const int t2 = tid >> 7;           // 0..3
    const int n2 = (tid & 127) * 2;    // 0..254

    const float* w1j = w1 + (size_t)j * DIM * HID;

    // ---- prefetch B chunk (nt=0, kc=0) into regs: overlaps the LN phase ----
    float la[8][2];
    {
        const float* bp = w1j + (size_t)(8 * t2) * HID + n2;
        #pragma unroll
        for (int i = 0; i < 8; ++i) {
            la[i][0] = bp[i * HID + 0];
            la[i][1] = bp[i * HID + 1];
        }
    }

    // ---- Phase 1: LayerNorm -> A_lds (bf16, swizzled). wave wv: rows 16*wv.. ----
    {
        const float4* gp = (const float4*)(gamma + lane * 8);
        const float4* bpp = (const float4*)(beta + lane * 8);
        float4 g0 = gp[0], g1 = gp[1];
        float4 e0 = bpp[0], e1 = bpp[1];
        #pragma unroll 1
        for (int rr = 0; rr < 16; ++rr) {
            int m  = wv * 16 + rr;
            int gr = mt * BM + m;          // token index
            float4 xa = {0.f,0.f,0.f,0.f}, xb = {0.f,0.f,0.f,0.f};
            if (gr < MTOT) {
                const float4* xp = (const float4*)(x + ((size_t)gr * JN + j) * DIM + lane * 8);
                xa = xp[0]; xb = xp[1];
            }
            float s  = ((xa.x + xa.y) + (xa.z + xa.w)) + ((xb.x + xb.y) + (xb.z + xb.w));
            float s2 = fmaf(xa.x, xa.x, fmaf(xa.y, xa.y, fmaf(xa.z, xa.z, fmaf(xa.w, xa.w,
                       fmaf(xb.x, xb.x, fmaf(xb.y, xb.y, fmaf(xb.z, xb.z, xb.w * xb.w)))))));
            #pragma unroll
            for (int d = 1; d < 64; d <<= 1) {
                s  += __shfl_xor(s,  d);
                s2 += __shfl_xor(s2, d);
            }
            float mu  = s * (1.0f / 512.0f);
            float var = s2 * (1.0f / 512.0f) - mu * mu;
            float rs  = rsqrtf(var + 1e-5f);
            uint4 qq = {0u, 0u, 0u, 0u};
            if (gr < MTOT) {
                float v0 = fmaf((xa.x - mu) * rs, g0.x, e0.x);
                float v1 = fmaf((xa.y - mu) * rs, g0.y, e0.y);
                float v2 = fmaf((xa.z - mu) * rs, g0.z, e0.z);
                float v3 = fmaf((xa.w - mu) * rs, g0.w, e0.w);
                float v4 = fmaf((xb.x - mu) * rs, g1.x, e1.x);
                float v5 = fmaf((xb.y - mu) * rs, g1.y, e1.y);
                float v6 = fmaf((xb.z - mu) * rs, g1.z, e1.z);
                float v7 = fmaf((xb.w - mu) * rs, g1.w, e1.w);
                qq.x = f2bf(v0) | (f2bf(v1) << 16);
                qq.y = f2bf(v2) | (f2bf(v3) << 16);
                qq.z = f2bf(v4) | (f2bf(v5) << 16);
                qq.w = f2bf(v6) | (f2bf(v7) << 16);
            }
            *(uint4*)(smem + A_OFF + m * 1024 + ((lane ^ (m & 7)) * 16)) = qq;
        }
    }

    // ---- Phase 2: fc1 MFMA + fused GELU + fc2 partials ----
    float yr[4][4][3];
    #pragma unroll
    for (int a = 0; a < 4; ++a)
        #pragma unroll
        for (int r = 0; r < 4; ++r)
            #pragma unroll
            for (int o = 0; o < 3; ++o) yr[a][r][o] = 0.f;

    const f32x4 zero4 = {0.f, 0.f, 0.f, 0.f};

    #pragma unroll 1
    for (int nt = 0; nt < 4; ++nt) {
        f32x4 acc[4][4];
        #pragma unroll
        for (int mf = 0; mf < 4; ++mf)
            #pragma unroll
            for (int nf = 0; nf < 4; ++nf) acc[mf][nf] = zero4;

        #pragma unroll 1
        for (int kci = 0; kci < 16; ++kci) {
            __syncthreads();   // previous compute done reading B_lds (also drains la loads)
            // staged regs -> B_lds (bf16, transposed to [n][k], unit-swizzled)
            #pragma unroll
            for (int u = 0; u < 2; ++u) {
                int n = n2 + u;
                uint4 qq;
                qq.x = f2bf(la[0][u]) | (f2bf(la[1][u]) << 16);
                qq.y = f2bf(la[2][u]) | (f2bf(la[3][u]) << 16);
                qq.z = f2bf(la[4][u]) | (f2bf(la[5][u]) << 16);
                qq.w = f2bf(la[6][u]) | (f2bf(la[7][u]) << 16);
                int phys = t2 ^ ((n >> 1) & 3);
                *(uint4*)(smem + B_OFF + n * 64 + phys * 16) = qq;
            }
            __syncthreads();   // B_lds ready
            // prefetch next chunk (latency hides under the MFMAs below)
            int gt = nt * 16 + kci;
            if (gt + 1 < 64) {
                int nnt = (gt + 1) >> 4;
                int nkc = ((gt + 1) & 15) * BK;
                const float* bp = w1j + (size_t)(nkc + 8 * t2) * HID + nnt * BN + n2;
                #pragma unroll
                for (int i = 0; i < 8; ++i) {
                    la[i][0] = bp[i * HID + 0];
                    la[i][1] = bp[i * HID + 1];
                }
            }
            // fragments + 16 MFMAs
            int kc = kci * BK;
            s16x8 aF[4], bF[4];
            #pragma unroll
            for (int mf = 0; mf < 4; ++mf) {
                int m  = wm * 64 + mf * 16 + (lane & 15);
                int ul = (kc >> 3) + (lane >> 4);
                aF[mf] = *(const s16x8*)(smem + A_OFF + m * 1024 + ((ul ^ (m & 7)) * 16));
            }
            #pragma unroll
            for (int nf = 0; nf < 4; ++nf) {
                int n  = wn * 64 + nf * 16 + (lane & 15);
                int ph = (lane >> 4) ^ ((n >> 1) & 3);
                bF[nf] = *(const s16x8*)(smem + B_OFF + n * 64 + ph * 16);
            }
            #pragma unroll
            for (int mf = 0; mf < 4; ++mf)
                #pragma unroll
                for (int nf = 0; nf < 4; ++nf)
                    acc[mf][nf] = __builtin_amdgcn_mfma_f32_16x16x32_bf16(aF[mf], bF[nf], acc[mf][nf], 0, 0, 0);
        }

        // epilogue: bias + exact GELU + fc2 partial accumulation (all in regs)
        #pragma unroll
        for (int nf = 0; nf < 4; ++nf) {
            int n = nt * BN + wn * 64 + nf * 16 + (lane & 15);
            float b1v = b1[j * HID + n];
            const float* w2p = w2 + ((size_t)j * HID + n) * 3;
            float w20 = w2p[0], w21 = w2p[1], w22 = w2p[2];
            #pragma unroll
            for (int mf = 0; mf < 4; ++mf) {
                #pragma unroll
                for (int r = 0; r < 4; ++r) {
                    float g = gelu_erf(acc[mf][nf][r] + b1v);
                    yr[mf][r][0] = fmaf(g, w20, yr[mf][r][0]);
                    yr[mf][r][1] = fmaf(g, w21, yr[mf][r][1]);
                    yr[mf][r][2] = fmaf(g, w22, yr[mf][r][2]);
                }
            }
        }
    }

    // ---- reduce fc2 partials across the 16 n-lanes, stash per-wn plane ----
    #pragma unroll
    for (int mf = 0; mf < 4; ++mf)
        #pragma unroll
        for (int r = 0; r < 4; ++r)
            #pragma unroll
            for (int o = 0; o < 3; ++o) {
                float v = yr[mf][r][o];
                v += __shfl_xor(v, 1);
                v += __shfl_xor(v, 2);
                v += __shfl_xor(v, 4);
                v += __shfl_xor(v, 8);
                yr[mf][r][o] = v;
            }

    float* Yp = (float*)(smem + Y_OFF);
    if ((lane & 15) == 0) {
        int mrow = lane >> 4;   // 0..3
        #pragma unroll
        for (int mf = 0; mf < 4; ++mf)
            #pragma unroll
            for (int r = 0; r < 4; ++r) {
                int m = wm * 64 + mf * 16 + mrow * 4 + r;
                #pragma unroll
                for (int o = 0; o < 3; ++o)
                    Yp[(wn * BM + m) * 3 + o] = yr[mf][r][o];
            }
    }
    __syncthreads();

    if (tid < BM * 3) {
        int m = tid / 3;
        int o = tid - m * 3;
        int gr = mt * BM + m;
        if (gr < MTOT) {
            float v = Yp[m * 3 + o] + Yp[(BM + m) * 3 + o]
                    + Yp[(2 * BM + m) * 3 + o] + Yp[(3 * BM + m) * 3 + o]
                    + b2[j * 3 + o];
            out[((size_t)gr * JN + j) * 3 + o] = v;
        }
    }
}

extern "C" void kernel_launch(void* const* d_in, const int* in_sizes, int n_in,
                              void* d_out, int out_size, void* d_ws, size_t ws_size,
                              hipStream_t stream) {
    (void)in_sizes; (void)n_in; (void)out_size; (void)d_ws; (void)ws_size;
    const float* x   = (const float*)d_in[0];
    const float* ga  = (const float*)d_in[1];
    const float* be  = (const float*)d_in[2];
    const float* w1  = (const float*)d_in[3];
    const float* b1  = (const float*)d_in[4];
    const float* w2  = (const float*)d_in[5];
    const float* b2  = (const float*)d_in[6];
    float* out = (float*)d_out;

    hipFuncSetAttribute((const void*)pjh_fused,
                        hipFuncAttributeMaxDynamicSharedMemorySize, SMEM_BYTES);
    dim3 grid((MTOT + BM - 1) / BM, JN);   // 61 x 17
    pjh_fused<<<grid, NTHR, SMEM_BYTES, stream>>>(x, ga, be, w1, b1, w2, b2, out);
}

// Round 3
// 344.609 us; speedup vs baseline: 1.4059x; 1.4059x over previous
//
#include <hip/hip_runtime.h>
#include <hip/hip_bf16.h>

#define JN   17
#define DIM  512
#define HID  1024
#define MTOT 7776      // B*T = 32*243
#define BM   128
#define BN   256
#define BK   32
#define NTHR 512

typedef __attribute__((ext_vector_type(8))) short s16x8;
typedef __attribute__((ext_vector_type(4))) float f32x4;
typedef unsigned short ushort_t;

__device__ __forceinline__ unsigned int f2bf(float f) {
    return (unsigned int)__builtin_bit_cast(unsigned short, __float2bfloat16(f));
}

// exact-erf GELU via Abramowitz-Stegun 7.1.26 (|err| < 1.5e-7)
__device__ __forceinline__ float gelu_erf(float h) {
    float ah = fabsf(h);
    float z  = ah * 0.7071067811865476f;
    float t  = __builtin_amdgcn_rcpf(fmaf(0.3275911f, z, 1.0f));
    float p  = fmaf(fmaf(fmaf(fmaf(1.061405429f, t, -1.453152027f), t,
                              1.421413741f), t, -0.284496736f), t, 0.254829592f);
    float er = 1.0f - p * t * __expf(-z * z);   // erf(|z|) in [0,1)
    return fmaf(0.5f * ah, er, 0.5f * h);       // 0.5h(1+sgn(h)erf(|z|))
}

// ============================================================================
// Prepass: w1 [J][512][1024] fp32  ->  w1s [J][kc=16][n=1024][p=4][8] bf16
// p = u ^ ((n>>1)&3)  (pre-swizzled so global_load_lds' linear LDS dest lands
// the XOR-swizzled layout; read side applies the same XOR)
// ============================================================================
__global__ __launch_bounds__(256)
void prep_w1(const float* __restrict__ w1, ushort_t* __restrict__ w1s) {
    int b  = blockIdx.x;          // j*64 + kc*4 + nq
    int nq = b & 3;
    int kc = (b >> 2) & 15;
    int j  = b >> 6;
    int n  = nq * 256 + threadIdx.x;

    const float* src = w1 + ((size_t)j * DIM + kc * 32) * HID + n;
    ushort_t* dst = w1s + (((size_t)j * 16 + kc) * 1024 + n) * 32;

    #pragma unroll
    for (int u = 0; u < 4; ++u) {
        float v[8];
        #pragma unroll
        for (int e = 0; e < 8; ++e) v[e] = src[(u * 8 + e) * HID];
        uint4 qq;
        qq.x = f2bf(v[0]) | (f2bf(v[1]) << 16);
        qq.y = f2bf(v[2]) | (f2bf(v[3]) << 16);
        qq.z = f2bf(v[4]) | (f2bf(v[5]) << 16);
        qq.w = f2bf(v[6]) | (f2bf(v[7]) << 16);
        int p = u ^ ((n >> 1) & 3);
        *(uint4*)(dst + p * 8) = qq;
    }
}

// ============================================================================
// Main fused kernel v2: LN -> A_lds resident; B via global_load_lds dbuf;
// fc1 MFMA + GELU + fc2 partials in regs.
// LDS: A [128][512] bf16 swizzled = 131072 ; B dbuf 2x16384 ; Y overlays B.
// ============================================================================
#define A_OFF 0
#define B_OFF 131072
#define Y_OFF 131072          // overlays B buffer 0 (only used after final barrier)
#define SMEM_V2 163840

__global__ __launch_bounds__(NTHR, 2)
void pjh_fused_v2(const float* __restrict__ x,
                  const float* __restrict__ gamma,
                  const float* __restrict__ beta,
                  const ushort_t* __restrict__ w1s,
                  const float* __restrict__ b1,
                  const float* __restrict__ w2,
                  const float* __restrict__ b2,
                  float* __restrict__ out)
{
    extern __shared__ char smem[];
    const int tid  = threadIdx.x;
    const int lane = tid & 63;
    const int wv   = tid >> 6;   // 0..7
    const int wm   = wv >> 2;    // 0..1
    const int wn   = wv & 3;     // 0..3
    const int mt   = blockIdx.x; // 0..60
    const int j    = blockIdx.y; // 0..16

    const ushort_t* w1j = w1s + (size_t)j * 16 * 1024 * 32;   // [kc][n][p][8]

    // ---- issue B tile 0 (kc=0, nt=0) into buf0 while LN runs ----
    {
        const ushort_t* tb = w1j;   // kc=0, n0=0
        #pragma unroll
        for (int q = 0; q < 2; ++q) {
            const ushort_t* src = tb + (size_t)(wv * 2 + q) * 512 + lane * 8;
            void* dst = smem + B_OFF + (wv * 2 + q) * 1024;
            __builtin_amdgcn_global_load_lds(
                (const __attribute__((address_space(1))) unsigned int*)src,
                (__attribute__((address_space(3))) unsigned int*)dst, 16, 0, 0);
        }
    }

    // ---- Phase 1: LayerNorm -> A_lds (bf16, unit-swizzled), 4 rows batched ----
    {
        const float4* gp  = (const float4*)(gamma + lane * 8);
        const float4* bpp = (const float4*)(beta + lane * 8);
        float4 g0 = gp[0], g1 = gp[1];
        float4 e0 = bpp[0], e1 = bpp[1];
        #pragma unroll 1
        for (int rb = 0; rb < 16; rb += 4) {
            float4 xs[4][2];
            #pragma unroll
            for (int r = 0; r < 4; ++r) {
                int gr = mt * BM + wv * 16 + rb + r;
                if (gr < MTOT) {
                    const float4* xp = (const float4*)(x + ((size_t)gr * JN + j) * DIM + lane * 8);
                    xs[r][0] = xp[0]; xs[r][1] = xp[1];
                } else {
                    xs[r][0] = make_float4(0.f,0.f,0.f,0.f);
                    xs[r][1] = make_float4(0.f,0.f,0.f,0.f);
                }
            }
            #pragma unroll
            for (int r = 0; r < 4; ++r) {
                int m = wv * 16 + rb + r;
                float4 xa = xs[r][0], xb = xs[r][1];
                float s  = ((xa.x + xa.y) + (xa.z + xa.w)) + ((xb.x + xb.y) + (xb.z + xb.w));
                float s2 = fmaf(xa.x, xa.x, fmaf(xa.y, xa.y, fmaf(xa.z, xa.z, fmaf(xa.w, xa.w,
                           fmaf(xb.x, xb.x, fmaf(xb.y, xb.y, fmaf(xb.z, xb.z, xb.w * xb.w)))))));
                #pragma unroll
                for (int d = 1; d < 64; d <<= 1) {
                    s  += __shfl_xor(s,  d);
                    s2 += __shfl_xor(s2, d);
                }
                float mu  = s * (1.0f / 512.0f);
                float var = s2 * (1.0f / 512.0f) - mu * mu;
                float rs  = rsqrtf(var + 1e-5f);
                float v0 = fmaf((xa.x - mu) * rs, g0.x, e0.x);
                float v1 = fmaf((xa.y - mu) * rs, g0.y, e0.y);
                float v2 = fmaf((xa.z - mu) * rs, g0.z, e0.z);
                float v3 = fmaf((xa.w - mu) * rs, g0.w, e0.w);
                float v4 = fmaf((xb.x - mu) * rs, g1.x, e1.x);
                float v5 = fmaf((xb.y - mu) * rs, g1.y, e1.y);
                float v6 = fmaf((xb.z - mu) * rs, g1.z, e1.z);
                float v7 = fmaf((xb.w - mu) * rs, g1.w, e1.w);
                uint4 qq;
                qq.x = f2bf(v0) | (f2bf(v1) << 16);
                qq.y = f2bf(v2) | (f2bf(v3) << 16);
                qq.z = f2bf(v4) | (f2bf(v5) << 16);
                qq.w = f2bf(v6) | (f2bf(v7) << 16);
                *(uint4*)(smem + A_OFF + m * 1024 + ((lane ^ (m & 7)) * 16)) = qq;
            }
        }
    }

    __syncthreads();   // A ready; B tile 0 drained (vmcnt)

    // ---- Phase 2: 64 B-tiles (nt 0..3 x kc 0..15), single barrier each ----
    float yr[4][4][3];
    #pragma unroll
    for (int a = 0; a < 4; ++a)
        #pragma unroll
        for (int r = 0; r < 4; ++r)
            #pragma unroll
            for (int o = 0; o < 3; ++o) yr[a][r][o] = 0.f;

    const f32x4 zero4 = {0.f, 0.f, 0.f, 0.f};
    f32x4 acc[4][4];
    #pragma unroll
    for (int mf = 0; mf < 4; ++mf)
        #pragma unroll
        for (int nf = 0; nf < 4; ++nf) acc[mf][nf] = zero4;

    #pragma unroll 1
    for (int t = 0; t < 64; ++t) {
        // issue next tile into other buffer (drained by this iter's syncthreads)
        if (t + 1 < 64) {
            int kc = (t + 1) & 15, nt = (t + 1) >> 4;
            const ushort_t* tb = w1j + ((size_t)kc * 1024 + nt * 256) * 32;
            int bb = ((t + 1) & 1) * 16384;
            #pragma unroll
            for (int q = 0; q < 2; ++q) {
                const ushort_t* src = tb + (size_t)(wv * 2 + q) * 512 + lane * 8;
                void* dst = smem + B_OFF + bb + (wv * 2 + q) * 1024;
                __builtin_amdgcn_global_load_lds(
                    (const __attribute__((address_space(1))) unsigned int*)src,
                    (__attribute__((address_space(3))) unsigned int*)dst, 16, 0, 0);
            }
        }

        // fragments from resident A and current B buffer
        int kc = t & 15;
        int bb = (t & 1) * 16384;
        int g  = lane >> 4;
        s16x8 aF[4], bF[4];
        #pragma unroll
        for (int mf = 0; mf < 4; ++mf) {
            int m  = wm * 64 + mf * 16 + (lane & 15);
            int ul = kc * 4 + g;
            aF[mf] = *(const s16x8*)(smem + A_OFF + m * 1024 + ((ul ^ (m & 7)) * 16));
        }
        #pragma unroll
        for (int nf = 0; nf < 4; ++nf) {
            int nl = wn * 64 + nf * 16 + (lane & 15);          // n within tile
            int p  = g ^ ((nl >> 1) & 3);                      // swizzle bits n1..n2
            bF[nf] = *(const s16x8*)(smem + B_OFF + bb + (nl * 4 + p) * 16);
        }
        #pragma unroll
        for (int mf = 0; mf < 4; ++mf)
            #pragma unroll
            for (int nf = 0; nf < 4; ++nf)
                acc[mf][nf] = __builtin_amdgcn_mfma_f32_16x16x32_bf16(aF[mf], bF[nf], acc[mf][nf], 0, 0, 0);

        // epilogue at end of each K sweep: bias + GELU + fc2 partials (regs only)
        if ((t & 15) == 15) {
            int nt = t >> 4;
            #pragma unroll
            for (int nf = 0; nf < 4; ++nf) {
                int n = nt * BN + wn * 64 + nf * 16 + (lane & 15);
                float b1v = b1[j * HID + n];
                const float* w2p = w2 + ((size_t)j * HID + n) * 3;
                float w20 = w2p[0], w21 = w2p[1], w22 = w2p[2];
                #pragma unroll
                for (int mf = 0; mf < 4; ++mf) {
                    #pragma unroll
                    for (int r = 0; r < 4; ++r) {
                        float gv = gelu_erf(acc[mf][nf][r] + b1v);
                        yr[mf][r][0] = fmaf(gv, w20, yr[mf][r][0]);
                        yr[mf][r][1] = fmaf(gv, w21, yr[mf][r][1]);
                        yr[mf][r][2] = fmaf(gv, w22, yr[mf][r][2]);
                    }
                }
            }
            // zero ALL accumulators only after the whole epilogue has consumed them
            #pragma unroll
            for (int mf = 0; mf < 4; ++mf)
                #pragma unroll
                for (int nf = 0; nf < 4; ++nf)
                    acc[mf][nf] = zero4;
        }
        __syncthreads();
    }

    // ---- reduce fc2 partials across 16 n-lanes; stash per-wn plane in LDS ----
    #pragma unroll
    for (int mf = 0; mf < 4; ++mf)
        #pragma unroll
        for (int r = 0; r < 4; ++r)
            #pragma unroll
            for (int o = 0; o < 3; ++o) {
                float v = yr[mf][r][o];
                v += __shfl_xor(v, 1);
                v += __shfl_xor(v, 2);
                v += __shfl_xor(v, 4);
                v += __shfl_xor(v, 8);
                yr[mf][r][o] = v;
            }

    float* Yp = (float*)(smem + Y_OFF);
    if ((lane & 15) == 0) {
        int mrow = lane >> 4;
        #pragma unroll
        for (int mf = 0; mf < 4; ++mf)
            #pragma unroll
            for (int r = 0; r < 4; ++r) {
                int m = wm * 64 + mf * 16 + mrow * 4 + r;
                #pragma unroll
                for (int o = 0; o < 3; ++o)
                    Yp[(wn * BM + m) * 3 + o] = yr[mf][r][o];
            }
    }
    __syncthreads();

    if (tid < BM * 3) {
        int m = tid / 3;
        int o = tid - m * 3;
        int gr = mt * BM + m;
        if (gr < MTOT) {
            float v = Yp[m * 3 + o] + Yp[(BM + m) * 3 + o]
                    + Yp[(2 * BM + m) * 3 + o] + Yp[(3 * BM + m) * 3 + o]
                    + b2[j * 3 + o];
            out[((size_t)gr * JN + j) * 3 + o] = v;
        }
    }
}

// ============================================================================
// Fallback v1 (round-1 kernel, used only if ws_size can't hold w1s)
// ============================================================================
#define A1_OFF 0
#define B1_OFF 131072
#define Y1_OFF 147456
#define SMEM_V1 153600

__global__ __launch_bounds__(NTHR, 2)
void pjh_fused_v1(const float* __restrict__ x,
                  const float* __restrict__ gamma,
                  const float* __restrict__ beta,
                  const float* __restrict__ w1,
                  const float* __restrict__ b1,
                  const float* __restrict__ w2,
                  const float* __restrict__ b2,
                  float* __restrict__ out)
{
    extern __shared__ char smem[];
    const int tid  = threadIdx.x;
    const int lane = tid & 63;
    const int wv   = tid >> 6;
    const int wm   = wv >> 2;
    const int wn   = wv & 3;
    const int mt   = blockIdx.x;
    const int j    = blockIdx.y;
    const int t2 = tid >> 7;
    const int n2 = (tid & 127) * 2;
    const float* w1j = w1 + (size_t)j * DIM * HID;

    float la[8][2];
    {
        const float* bp = w1j + (size_t)(8 * t2) * HID + n2;
        #pragma unroll
        for (int i = 0; i < 8; ++i) { la[i][0] = bp[i * HID + 0]; la[i][1] = bp[i * HID + 1]; }
    }
    {
        const float4* gp = (const float4*)(gamma + lane * 8);
        const float4* bpp = (const float4*)(beta + lane * 8);
        float4 g0 = gp[0], g1 = gp[1];
        float4 e0 = bpp[0], e1 = bpp[1];
        #pragma unroll 1
        for (int rr = 0; rr < 16; ++rr) {
            int m  = wv * 16 + rr;
            int gr = mt * BM + m;
            float4 xa = {0.f,0.f,0.f,0.f}, xb = {0.f,0.f,0.f,0.f};
            if (gr < MTOT) {
                const float4* xp = (const float4*)(x + ((size_t)gr * JN + j) * DIM + lane * 8);
                xa = xp[0]; xb = xp[1];
            }
            float s  = ((xa.x + xa.y) + (xa.z + xa.w)) + ((xb.x + xb.y) + (xb.z + xb.w));
            float s2 = fmaf(xa.x, xa.x, fmaf(xa.y, xa.y, fmaf(xa.z, xa.z, fmaf(xa.w, xa.w,
                       fmaf(xb.x, xb.x, fmaf(xb.y, xb.y, fmaf(xb.z, xb.z, xb.w * xb.w)))))));
            #pragma unroll
            for (int d = 1; d < 64; d <<= 1) { s += __shfl_xor(s, d); s2 += __shfl_xor(s2, d); }
            float mu  = s * (1.0f / 512.0f);
            float var = s2 * (1.0f / 512.0f) - mu * mu;
            float rs  = rsqrtf(var + 1e-5f);
            uint4 qq = {0u,0u,0u,0u};
            if (gr < MTOT) {
                float v0 = fmaf((xa.x - mu) * rs, g0.x, e0.x);
                float v1 = fmaf((xa.y - mu) * rs, g0.y, e0.y);
                float v2 = fmaf((xa.z - mu) * rs, g0.z, e0.z);
                float v3 = fmaf((xa.w - mu) * rs, g0.w, e0.w);
                float v4 = fmaf((xb.x - mu) * rs, g1.x, e1.x);
                float v5 = fmaf((xb.y - mu) * rs, g1.y, e1.y);
                float v6 = fmaf((xb.z - mu) * rs, g1.z, e1.z);
                float v7 = fmaf((xb.w - mu) * rs, g1.w, e1.w);
                qq.x = f2bf(v0) | (f2bf(v1) << 16);
                qq.y = f2bf(v2) | (f2bf(v3) << 16);
                qq.z = f2bf(v4) | (f2bf(v5) << 16);
                qq.w = f2bf(v6) | (f2bf(v7) << 16);
            }
            *(uint4*)(smem + A1_OFF + m * 1024 + ((lane ^ (m & 7)) * 16)) = qq;
        }
    }

    float yr[4][4][3];
    #pragma unroll
    for (int a = 0; a < 4; ++a)
        #pragma unroll
        for (int r = 0; r < 4; ++r)
            #pragma unroll
            for (int o = 0; o < 3; ++o) yr[a][r][o] = 0.f;
    const f32x4 zero4 = {0.f,0.f,0.f,0.f};

    #pragma unroll 1
    for (int nt = 0; nt < 4; ++nt) {
        f32x4 acc[4][4];
        #pragma unroll
        for (int mf = 0; mf < 4; ++mf)
            #pragma unroll
            for (int nf = 0; nf < 4; ++nf) acc[mf][nf] = zero4;
        #pragma unroll 1
        for (int kci = 0; kci < 16; ++kci) {
            __syncthreads();
            #pragma unroll
            for (int u = 0; u < 2; ++u) {
                int n = n2 + u;
                uint4 qq;
                qq.x = f2bf(la[0][u]) | (f2bf(la[1][u]) << 16);
                qq.y = f2bf(la[2][u]) | (f2bf(la[3][u]) << 16);
                qq.z = f2bf(la[4][u]) | (f2bf(la[5][u]) << 16);
                qq.w = f2bf(la[6][u]) | (f2bf(la[7][u]) << 16);
                int phys = t2 ^ ((n >> 1) & 3);
                *(uint4*)(smem + B1_OFF + n * 64 + phys * 16) = qq;
            }
            __syncthreads();
            int gt = nt * 16 + kci;
            if (gt + 1 < 64) {
                int nnt = (gt + 1) >> 4;
                int nkc = ((gt + 1) & 15) * BK;
                const float* bp = w1j + (size_t)(nkc + 8 * t2) * HID + nnt * BN + n2;
                #pragma unroll
                for (int i = 0; i < 8; ++i) { la[i][0] = bp[i * HID + 0]; la[i][1] = bp[i * HID + 1]; }
            }
            int kc = kci * BK;
            s16x8 aF[4], bF[4];
            #pragma unroll
            for (int mf = 0; mf < 4; ++mf) {
                int m  = wm * 64 + mf * 16 + (lane & 15);
                int ul = (kc >> 3) + (lane >> 4);
                aF[mf] = *(const s16x8*)(smem + A1_OFF + m * 1024 + ((ul ^ (m & 7)) * 16));
            }
            #pragma unroll
            for (int nf = 0; nf < 4; ++nf) {
                int n  = wn * 64 + nf * 16 + (lane & 15);
                int ph = (lane >> 4) ^ ((n >> 1) & 3);
                bF[nf] = *(const s16x8*)(smem + B1_OFF + n * 64 + ph * 16);
            }
            #pragma unroll
            for (int mf = 0; mf < 4; ++mf)
                #pragma unroll
                for (int nf = 0; nf < 4; ++nf)
                    acc[mf][nf] = __builtin_amdgcn_mfma_f32_16x16x32_bf16(aF[mf], bF[nf], acc[mf][nf], 0, 0, 0);
        }
        #pragma unroll
        for (int nf = 0; nf < 4; ++nf) {
            int n = nt * BN + wn * 64 + nf * 16 + (lane & 15);
            float b1v = b1[j * HID + n];
            const float* w2p = w2 + ((size_t)j * HID + n) * 3;
            float w20 = w2p[0], w21 = w2p[1], w22 = w2p[2];
            #pragma unroll
            for (int mf = 0; mf < 4; ++mf)
                #pragma unroll
                for (int r = 0; r < 4; ++r) {
                    float gv = gelu_erf(acc[mf][nf][r] + b1v);
                    yr[mf][r][0] = fmaf(gv, w20, yr[mf][r][0]);
                    yr[mf][r][1] = fmaf(gv, w21, yr[mf][r][1]);
                    yr[mf][r][2] = fmaf(gv, w22, yr[mf][r][2]);
                }
        }
    }
    #pragma unroll
    for (int mf = 0; mf < 4; ++mf)
        #pragma unroll
        for (int r = 0; r < 4; ++r)
            #pragma unroll
            for (int o = 0; o < 3; ++o) {
                float v = yr[mf][r][o];
                v += __shfl_xor(v, 1); v += __shfl_xor(v, 2);
                v += __shfl_xor(v, 4); v += __shfl_xor(v, 8);
                yr[mf][r][o] = v;
            }
    float* Yp = (float*)(smem + Y1_OFF);
    if ((lane & 15) == 0) {
        int mrow = lane >> 4;
        #pragma unroll
        for (int mf = 0; mf < 4; ++mf)
            #pragma unroll
            for (int r = 0; r < 4; ++r) {
                int m = wm * 64 + mf * 16 + mrow * 4 + r;
                #pragma unroll
                for (int o = 0; o < 3; ++o) Yp[(wn * BM + m) * 3 + o] = yr[mf][r][o];
            }
    }
    __syncthreads();
    if (tid < BM * 3) {
        int m = tid / 3;
        int o = tid - m * 3;
        int gr = mt * BM + m;
        if (gr < MTOT) {
            float v = Yp[m * 3 + o] + Yp[(BM + m) * 3 + o]
                    + Yp[(2 * BM + m) * 3 + o] + Yp[(3 * BM + m) * 3 + o]
                    + b2[j * 3 + o];
            out[((size_t)gr * JN + j) * 3 + o] = v;
        }
    }
}

extern "C" void kernel_launch(void* const* d_in, const int* in_sizes, int n_in,
                              void* d_out, int out_size, void* d_ws, size_t ws_size,
                              hipStream_t stream) {
    (void)in_sizes; (void)n_in; (void)out_size;
    const float* x   = (const float*)d_in[0];
    const float* ga  = (const float*)d_in[1];
    const float* be  = (const float*)d_in[2];
    const float* w1  = (const float*)d_in[3];
    const float* b1  = (const float*)d_in[4];
    const float* w2  = (const float*)d_in[5];
    const float* b2  = (const float*)d_in[6];
    float* out = (float*)d_out;

    const size_t w1s_bytes = (size_t)JN * 16 * 1024 * 4 * 8 * sizeof(ushort_t); // 17825792

    if (ws_size >= w1s_bytes) {
        ushort_t* w1s = (ushort_t*)d_ws;
        prep_w1<<<JN * 16 * 4, 256, 0, stream>>>(w1, w1s);
        hipFuncSetAttribute((const void*)pjh_fused_v2,
                            hipFuncAttributeMaxDynamicSharedMemorySize, SMEM_V2);
        dim3 grid((MTOT + BM - 1) / BM, JN);
        pjh_fused_v2<<<grid, NTHR, SMEM_V2, stream>>>(x, ga, be, w1s, b1, w2, b2, out);
    } else {
        hipFuncSetAttribute((const void*)pjh_fused_v1,
                            hipFuncAttributeMaxDynamicSharedMemorySize, SMEM_V1);
        dim3 grid((MTOT + BM - 1) / BM, JN);
        pjh_fused_v1<<<grid, NTHR, SMEM_V1, stream>>>(x, ga, be, w1, b1, w2, b2, out);
    }
}

// Round 4
// 328.570 us; speedup vs baseline: 1.4746x; 1.0488x over previous
//
#include <hip/hip_runtime.h>
#include <hip/hip_bf16.h>

#define JN   17
#define DIM  512
#define HID  1024
#define MTOT 7776      // B*T = 32*243
#define BN   256
#define BK   32
#define NTHR 512

typedef __attribute__((ext_vector_type(8))) short s16x8;
typedef __attribute__((ext_vector_type(4))) float f32x4;
typedef unsigned short ushort_t;

__device__ __forceinline__ unsigned int f2bf(float f) {
    return (unsigned int)__builtin_bit_cast(unsigned short, __float2bfloat16(f));
}

// exact-erf GELU via Abramowitz-Stegun 7.1.26 (|err| < 1.5e-7)
__device__ __forceinline__ float gelu_erf(float h) {
    float ah = fabsf(h);
    float z  = ah * 0.7071067811865476f;
    float t  = __builtin_amdgcn_rcpf(fmaf(0.3275911f, z, 1.0f));
    float p  = fmaf(fmaf(fmaf(fmaf(1.061405429f, t, -1.453152027f), t,
                              1.421413741f), t, -0.284496736f), t, 0.254829592f);
    float er = 1.0f - p * t * __expf(-z * z);   // erf(|z|) in [0,1)
    return fmaf(0.5f * ah, er, 0.5f * h);       // 0.5h(1+sgn(h)erf(|z|))
}

// ============================================================================
// Prepass: w1 [J][512][1024] fp32  ->  w1s [J][kc=16][n=1024][p=4][8] bf16
// p = u ^ ((n>>1)&3)  (pre-swizzled so global_load_lds' linear LDS dest lands
// the XOR-swizzled layout; read side applies the same XOR)
// ============================================================================
__global__ __launch_bounds__(256)
void prep_w1(const float* __restrict__ w1, ushort_t* __restrict__ w1s) {
    int b  = blockIdx.x;          // j*64 + kc*4 + nq
    int nq = b & 3;
    int kc = (b >> 2) & 15;
    int j  = b >> 6;
    int n  = nq * 256 + threadIdx.x;

    const float* src = w1 + ((size_t)j * DIM + kc * 32) * HID + n;
    ushort_t* dst = w1s + (((size_t)j * 16 + kc) * 1024 + n) * 32;

    #pragma unroll
    for (int u = 0; u < 4; ++u) {
        float v[8];
        #pragma unroll
        for (int e = 0; e < 8; ++e) v[e] = src[(u * 8 + e) * HID];
        uint4 qq;
        qq.x = f2bf(v[0]) | (f2bf(v[1]) << 16);
        qq.y = f2bf(v[2]) | (f2bf(v[3]) << 16);
        qq.z = f2bf(v[4]) | (f2bf(v[5]) << 16);
        qq.w = f2bf(v[6]) | (f2bf(v[7]) << 16);
        int p = u ^ ((n >> 1) & 3);
        *(uint4*)(dst + p * 8) = qq;
    }
}

// ============================================================================
// v3: BM=96 (7776 = 96*81, no tail), A resident 96KB, 4x16KB B ring buffers,
// depth-2 prefetch with counted vmcnt + raw s_barrier (T3+T4), setprio (T5).
// Waves 2x4, wave tile 48x64 (mf=3, nf=4).
// ============================================================================
#define BM3 96
#define A3_OFF 0            // 96*1024 = 98304
#define B3_OFF 98304        // 4 * 16384 = 65536
#define Y3_OFF 98304        // overlays B ring (used only after final __syncthreads)
#define SMEM_V3 163840

__global__ __launch_bounds__(NTHR, 2)
void pjh_fused_v3(const float* __restrict__ x,
                  const float* __restrict__ gamma,
                  const float* __restrict__ beta,
                  const ushort_t* __restrict__ w1s,
                  const float* __restrict__ b1,
                  const float* __restrict__ w2,
                  const float* __restrict__ b2,
                  float* __restrict__ out)
{
    extern __shared__ char smem[];
    const int tid  = threadIdx.x;
    const int lane = tid & 63;
    const int wv   = tid >> 6;   // 0..7
    const int wm   = wv >> 2;    // 0..1 : rows 48*wm
    const int wn   = wv & 3;     // 0..3 : cols 64*wn
    const int mt   = blockIdx.x; // 0..80
    const int j    = blockIdx.y; // 0..16

    const ushort_t* w1j = w1s + (size_t)j * 16 * 1024 * 32;   // [kc][n][p][8]

    // ---- prologue: issue tiles 0 and 1 into ring slots 0,1 (complete during LN)
    #pragma unroll
    for (int tt = 0; tt < 2; ++tt) {
        int kc = tt & 15, nt = 0;
        const ushort_t* tb = w1j + ((size_t)kc * 1024 + nt * 256) * 32;
        #pragma unroll
        for (int q = 0; q < 2; ++q) {
            const ushort_t* src = tb + (size_t)(wv * 2 + q) * 512 + lane * 8;
            void* dst = smem + B3_OFF + tt * 16384 + (wv * 2 + q) * 1024;
            __builtin_amdgcn_global_load_lds(
                (const __attribute__((address_space(1))) unsigned int*)src,
                (__attribute__((address_space(3))) unsigned int*)dst, 16, 0, 0);
        }
    }

    // ---- Phase 1: LayerNorm -> A_lds (bf16, unit-swizzled). 12 rows/wave ----
    {
        const float4* gp  = (const float4*)(gamma + lane * 8);
        const float4* bpp = (const float4*)(beta + lane * 8);
        float4 g0 = gp[0], g1 = gp[1];
        float4 e0 = bpp[0], e1 = bpp[1];
        #pragma unroll
        for (int rb = 0; rb < 12; rb += 4) {
            float4 xs[4][2];
            #pragma unroll
            for (int r = 0; r < 4; ++r) {
                int gr = mt * BM3 + wv * 12 + rb + r;   // always < MTOT (7776=96*81)
                const float4* xp = (const float4*)(x + ((size_t)gr * JN + j) * DIM + lane * 8);
                xs[r][0] = xp[0]; xs[r][1] = xp[1];
            }
            #pragma unroll
            for (int r = 0; r < 4; ++r) {
                int m = wv * 12 + rb + r;
                float4 xa = xs[r][0], xb = xs[r][1];
                float s  = ((xa.x + xa.y) + (xa.z + xa.w)) + ((xb.x + xb.y) + (xb.z + xb.w));
                float s2 = fmaf(xa.x, xa.x, fmaf(xa.y, xa.y, fmaf(xa.z, xa.z, fmaf(xa.w, xa.w,
                           fmaf(xb.x, xb.x, fmaf(xb.y, xb.y, fmaf(xb.z, xb.z, xb.w * xb.w)))))));
                #pragma unroll
                for (int d = 1; d < 64; d <<= 1) {
                    s  += __shfl_xor(s,  d);
                    s2 += __shfl_xor(s2, d);
                }
                float mu  = s * (1.0f / 512.0f);
                float var = s2 * (1.0f / 512.0f) - mu * mu;
                float rs  = rsqrtf(var + 1e-5f);
                float v0 = fmaf((xa.x - mu) * rs, g0.x, e0.x);
                float v1 = fmaf((xa.y - mu) * rs, g0.y, e0.y);
                float v2 = fmaf((xa.z - mu) * rs, g0.z, e0.z);
                float v3 = fmaf((xa.w - mu) * rs, g0.w, e0.w);
                float v4 = fmaf((xb.x - mu) * rs, g1.x, e1.x);
                float v5 = fmaf((xb.y - mu) * rs, g1.y, e1.y);
                float v6 = fmaf((xb.z - mu) * rs, g1.z, e1.z);
                float v7 = fmaf((xb.w - mu) * rs, g1.w, e1.w);
                uint4 qq;
                qq.x = f2bf(v0) | (f2bf(v1) << 16);
                qq.y = f2bf(v2) | (f2bf(v3) << 16);
                qq.z = f2bf(v4) | (f2bf(v5) << 16);
                qq.w = f2bf(v6) | (f2bf(v7) << 16);
                *(uint4*)(smem + A3_OFF + m * 1024 + ((lane ^ (m & 7)) * 16)) = qq;
            }
        }
    }

    __syncthreads();   // publishes A (lgkm drain) + drains tiles 0,1 (vmcnt 0)

    // ---- Phase 2: 64 tiles (nt 0..3 x kc 0..15), counted-vmcnt pipeline ----
    float yr[3][4][3];
    #pragma unroll
    for (int a = 0; a < 3; ++a)
        #pragma unroll
        for (int r = 0; r < 4; ++r)
            #pragma unroll
            for (int o = 0; o < 3; ++o) yr[a][r][o] = 0.f;

    const f32x4 zero4 = {0.f, 0.f, 0.f, 0.f};
    f32x4 acc[3][4];
    #pragma unroll
    for (int mf = 0; mf < 3; ++mf)
        #pragma unroll
        for (int nf = 0; nf < 4; ++nf) acc[mf][nf] = zero4;

    #pragma unroll 1
    for (int t = 0; t < 64; ++t) {
        // issue tile t+2 into ring slot (t+2)&3  (waited 2 iterations from now)
        if (t + 2 < 64) {
            int kc = (t + 2) & 15, nt = (t + 2) >> 4;
            const ushort_t* tb = w1j + ((size_t)kc * 1024 + nt * 256) * 32;
            int bb = ((t + 2) & 3) * 16384;
            #pragma unroll
            for (int q = 0; q < 2; ++q) {
                const ushort_t* src = tb + (size_t)(wv * 2 + q) * 512 + lane * 8;
                void* dst = smem + B3_OFF + bb + (wv * 2 + q) * 1024;
                __builtin_amdgcn_global_load_lds(
                    (const __attribute__((address_space(1))) unsigned int*)src,
                    (__attribute__((address_space(3))) unsigned int*)dst, 16, 0, 0);
            }
        }

        // fragments from resident A and ring slot t&3
        int kc = t & 15;
        int bb = (t & 3) * 16384;
        int g  = lane >> 4;
        s16x8 aF[3], bF[4];
        #pragma unroll
        for (int mf = 0; mf < 3; ++mf) {
            int m  = wm * 48 + mf * 16 + (lane & 15);
            int ul = kc * 4 + g;
            aF[mf] = *(const s16x8*)(smem + A3_OFF + m * 1024 + ((ul ^ (m & 7)) * 16));
        }
        #pragma unroll
        for (int nf = 0; nf < 4; ++nf) {
            int nl = wn * 64 + nf * 16 + (lane & 15);
            int p  = g ^ ((nl >> 1) & 3);
            bF[nf] = *(const s16x8*)(smem + B3_OFF + bb + (nl * 4 + p) * 16);
        }

        __builtin_amdgcn_s_setprio(1);
        #pragma unroll
        for (int mf = 0; mf < 3; ++mf)
            #pragma unroll
            for (int nf = 0; nf < 4; ++nf)
                acc[mf][nf] = __builtin_amdgcn_mfma_f32_16x16x32_bf16(aF[mf], bF[nf], acc[mf][nf], 0, 0, 0);
        __builtin_amdgcn_s_setprio(0);

        // end of each K sweep: bias + exact GELU + fc2 partials (regs only)
        if ((t & 15) == 15) {
            int nt = t >> 4;
            #pragma unroll
            for (int nf = 0; nf < 4; ++nf) {
                int n = nt * BN + wn * 64 + nf * 16 + (lane & 15);
                float b1v = b1[j * HID + n];
                const float* w2p = w2 + ((size_t)j * HID + n) * 3;
                float w20 = w2p[0], w21 = w2p[1], w22 = w2p[2];
                #pragma unroll
                for (int mf = 0; mf < 3; ++mf) {
                    #pragma unroll
                    for (int r = 0; r < 4; ++r) {
                        float gv = gelu_erf(acc[mf][nf][r] + b1v);
                        yr[mf][r][0] = fmaf(gv, w20, yr[mf][r][0]);
                        yr[mf][r][1] = fmaf(gv, w21, yr[mf][r][1]);
                        yr[mf][r][2] = fmaf(gv, w22, yr[mf][r][2]);
                    }
                }
            }
            #pragma unroll
            for (int mf = 0; mf < 3; ++mf)
                #pragma unroll
                for (int nf = 0; nf < 4; ++nf)
                    acc[mf][nf] = zero4;
        }

        // counted wait: leaves tile t+2's 2 loads in flight; confirms tile t+1
        if (t < 62) {
            asm volatile("s_waitcnt vmcnt(2)" ::: "memory");
        } else {
            asm volatile("s_waitcnt vmcnt(0)" ::: "memory");
        }
        __builtin_amdgcn_s_barrier();
    }

    // ---- reduce fc2 partials across 16 n-lanes; stash per-wn plane in LDS ----
    #pragma unroll
    for (int mf = 0; mf < 3; ++mf)
        #pragma unroll
        for (int r = 0; r < 4; ++r)
            #pragma unroll
            for (int o = 0; o < 3; ++o) {
                float v = yr[mf][r][o];
                v += __shfl_xor(v, 1);
                v += __shfl_xor(v, 2);
                v += __shfl_xor(v, 4);
                v += __shfl_xor(v, 8);
                yr[mf][r][o] = v;
            }

    __syncthreads();   // B ring dead; safe to overlay Y

    float* Yp = (float*)(smem + Y3_OFF);
    if ((lane & 15) == 0) {
        int mrow = lane >> 4;
        #pragma unroll
        for (int mf = 0; mf < 3; ++mf)
            #pragma unroll
            for (int r = 0; r < 4; ++r) {
                int m = wm * 48 + mf * 16 + mrow * 4 + r;
                #pragma unroll
                for (int o = 0; o < 3; ++o)
                    Yp[(wn * BM3 + m) * 3 + o] = yr[mf][r][o];
            }
    }
    __syncthreads();

    if (tid < BM3 * 3) {
        int m = tid / 3;
        int o = tid - m * 3;
        int gr = mt * BM3 + m;
        float v = Yp[m * 3 + o] + Yp[(BM3 + m) * 3 + o]
                + Yp[(2 * BM3 + m) * 3 + o] + Yp[(3 * BM3 + m) * 3 + o]
                + b2[j * 3 + o];
        out[((size_t)gr * JN + j) * 3 + o] = v;
    }
}

// ============================================================================
// Fallback v1 (round-1 kernel, used only if ws_size can't hold w1s)
// ============================================================================
#define BM   128
#define A1_OFF 0
#define B1_OFF 131072
#define Y1_OFF 147456
#define SMEM_V1 153600

__global__ __launch_bounds__(NTHR, 2)
void pjh_fused_v1(const float* __restrict__ x,
                  const float* __restrict__ gamma,
                  const float* __restrict__ beta,
                  const float* __restrict__ w1,
                  const float* __restrict__ b1,
                  const float* __restrict__ w2,
                  const float* __restrict__ b2,
                  float* __restrict__ out)
{
    extern __shared__ char smem[];
    const int tid  = threadIdx.x;
    const int lane = tid & 63;
    const int wv   = tid >> 6;
    const int wm   = wv >> 2;
    const int wn   = wv & 3;
    const int mt   = blockIdx.x;
    const int j    = blockIdx.y;
    const int t2 = tid >> 7;
    const int n2 = (tid & 127) * 2;
    const float* w1j = w1 + (size_t)j * DIM * HID;

    float la[8][2];
    {
        const float* bp = w1j + (size_t)(8 * t2) * HID + n2;
        #pragma unroll
        for (int i = 0; i < 8; ++i) { la[i][0] = bp[i * HID + 0]; la[i][1] = bp[i * HID + 1]; }
    }
    {
        const float4* gp = (const float4*)(gamma + lane * 8);
        const float4* bpp = (const float4*)(beta + lane * 8);
        float4 g0 = gp[0], g1 = gp[1];
        float4 e0 = bpp[0], e1 = bpp[1];
        #pragma unroll 1
        for (int rr = 0; rr < 16; ++rr) {
            int m  = wv * 16 + rr;
            int gr = mt * BM + m;
            float4 xa = {0.f,0.f,0.f,0.f}, xb = {0.f,0.f,0.f,0.f};
            if (gr < MTOT) {
                const float4* xp = (const float4*)(x + ((size_t)gr * JN + j) * DIM + lane * 8);
                xa = xp[0]; xb = xp[1];
            }
            float s  = ((xa.x + xa.y) + (xa.z + xa.w)) + ((xb.x + xb.y) + (xb.z + xb.w));
            float s2 = fmaf(xa.x, xa.x, fmaf(xa.y, xa.y, fmaf(xa.z, xa.z, fmaf(xa.w, xa.w,
                       fmaf(xb.x, xb.x, fmaf(xb.y, xb.y, fmaf(xb.z, xb.z, xb.w * xb.w)))))));
            #pragma unroll
            for (int d = 1; d < 64; d <<= 1) { s += __shfl_xor(s, d); s2 += __shfl_xor(s2, d); }
            float mu  = s * (1.0f / 512.0f);
            float var = s2 * (1.0f / 512.0f) - mu * mu;
            float rs  = rsqrtf(var + 1e-5f);
            uint4 qq = {0u,0u,0u,0u};
            if (gr < MTOT) {
                float v0 = fmaf((xa.x - mu) * rs, g0.x, e0.x);
                float v1 = fmaf((xa.y - mu) * rs, g0.y, e0.y);
                float v2 = fmaf((xa.z - mu) * rs, g0.z, e0.z);
                float v3 = fmaf((xa.w - mu) * rs, g0.w, e0.w);
                float v4 = fmaf((xb.x - mu) * rs, g1.x, e1.x);
                float v5 = fmaf((xb.y - mu) * rs, g1.y, e1.y);
                float v6 = fmaf((xb.z - mu) * rs, g1.z, e1.z);
                float v7 = fmaf((xb.w - mu) * rs, g1.w, e1.w);
                qq.x = f2bf(v0) | (f2bf(v1) << 16);
                qq.y = f2bf(v2) | (f2bf(v3) << 16);
                qq.z = f2bf(v4) | (f2bf(v5) << 16);
                qq.w = f2bf(v6) | (f2bf(v7) << 16);
            }
            *(uint4*)(smem + A1_OFF + m * 1024 + ((lane ^ (m & 7)) * 16)) = qq;
        }
    }

    float yr[4][4][3];
    #pragma unroll
    for (int a = 0; a < 4; ++a)
        #pragma unroll
        for (int r = 0; r < 4; ++r)
            #pragma unroll
            for (int o = 0; o < 3; ++o) yr[a][r][o] = 0.f;
    const f32x4 zero4 = {0.f,0.f,0.f,0.f};

    #pragma unroll 1
    for (int nt = 0; nt < 4; ++nt) {
        f32x4 acc[4][4];
        #pragma unroll
        for (int mf = 0; mf < 4; ++mf)
            #pragma unroll
            for (int nf = 0; nf < 4; ++nf) acc[mf][nf] = zero4;
        #pragma unroll 1
        for (int kci = 0; kci < 16; ++kci) {
            __syncthreads();
            #pragma unroll
            for (int u = 0; u < 2; ++u) {
                int n = n2 + u;
                uint4 qq;
                qq.x = f2bf(la[0][u]) | (f2bf(la[1][u]) << 16);
                qq.y = f2bf(la[2][u]) | (f2bf(la[3][u]) << 16);
                qq.z = f2bf(la[4][u]) | (f2bf(la[5][u]) << 16);
                qq.w = f2bf(la[6][u]) | (f2bf(la[7][u]) << 16);
                int phys = t2 ^ ((n >> 1) & 3);
                *(uint4*)(smem + B1_OFF + n * 64 + phys * 16) = qq;
            }
            __syncthreads();
            int gt = nt * 16 + kci;
            if (gt + 1 < 64) {
                int nnt = (gt + 1) >> 4;
                int nkc = ((gt + 1) & 15) * BK;
                const float* bp = w1j + (size_t)(nkc + 8 * t2) * HID + nnt * BN + n2;
                #pragma unroll
                for (int i = 0; i < 8; ++i) { la[i][0] = bp[i * HID + 0]; la[i][1] = bp[i * HID + 1]; }
            }
            int kc = kci * BK;
            s16x8 aF[4], bF[4];
            #pragma unroll
            for (int mf = 0; mf < 4; ++mf) {
                int m  = wm * 64 + mf * 16 + (lane & 15);
                int ul = (kc >> 3) + (lane >> 4);
                aF[mf] = *(const s16x8*)(smem + A1_OFF + m * 1024 + ((ul ^ (m & 7)) * 16));
            }
            #pragma unroll
            for (int nf = 0; nf < 4; ++nf) {
                int n  = wn * 64 + nf * 16 + (lane & 15);
                int ph = (lane >> 4) ^ ((n >> 1) & 3);
                bF[nf] = *(const s16x8*)(smem + B1_OFF + n * 64 + ph * 16);
            }
            #pragma unroll
            for (int mf = 0; mf < 4; ++mf)
                #pragma unroll
                for (int nf = 0; nf < 4; ++nf)
                    acc[mf][nf] = __builtin_amdgcn_mfma_f32_16x16x32_bf16(aF[mf], bF[nf], acc[mf][nf], 0, 0, 0);
        }
        #pragma unroll
        for (int nf = 0; nf < 4; ++nf) {
            int n = nt * BN + wn * 64 + nf * 16 + (lane & 15);
            float b1v = b1[j * HID + n];
            const float* w2p = w2 + ((size_t)j * HID + n) * 3;
            float w20 = w2p[0], w21 = w2p[1], w22 = w2p[2];
            #pragma unroll
            for (int mf = 0; mf < 4; ++mf)
                #pragma unroll
                for (int r = 0; r < 4; ++r) {
                    float gv = gelu_erf(acc[mf][nf][r] + b1v);
                    yr[mf][r][0] = fmaf(gv, w20, yr[mf][r][0]);
                    yr[mf][r][1] = fmaf(gv, w21, yr[mf][r][1]);
                    yr[mf][r][2] = fmaf(gv, w22, yr[mf][r][2]);
                }
        }
    }
    #pragma unroll
    for (int mf = 0; mf < 4; ++mf)
        #pragma unroll
        for (int r = 0; r < 4; ++r)
            #pragma unroll
            for (int o = 0; o < 3; ++o) {
                float v = yr[mf][r][o];
                v += __shfl_xor(v, 1); v += __shfl_xor(v, 2);
                v += __shfl_xor(v, 4); v += __shfl_xor(v, 8);
                yr[mf][r][o] = v;
            }
    float* Yp = (float*)(smem + Y1_OFF);
    if ((lane & 15) == 0) {
        int mrow = lane >> 4;
        #pragma unroll
        for (int mf = 0; mf < 4; ++mf)
            #pragma unroll
            for (int r = 0; r < 4; ++r) {
                int m = wm * 64 + mf * 16 + mrow * 4 + r;
                #pragma unroll
                for (int o = 0; o < 3; ++o) Yp[(wn * BM + m) * 3 + o] = yr[mf][r][o];
            }
    }
    __syncthreads();
    if (tid < BM * 3) {
        int m = tid / 3;
        int o = tid - m * 3;
        int gr = mt * BM + m;
        if (gr < MTOT) {
            float v = Yp[m * 3 + o] + Yp[(BM + m) * 3 + o]
                    + Yp[(2 * BM + m) * 3 + o] + Yp[(3 * BM + m) * 3 + o]
                    + b2[j * 3 + o];
            out[((size_t)gr * JN + j) * 3 + o] = v;
        }
    }
}

extern "C" void kernel_launch(void* const* d_in, const int* in_sizes, int n_in,
                              void* d_out, int out_size, void* d_ws, size_t ws_size,
                              hipStream_t stream) {
    (void)in_sizes; (void)n_in; (void)out_size;
    const float* x   = (const float*)d_in[0];
    const float* ga  = (const float*)d_in[1];
    const float* be  = (const float*)d_in[2];
    const float* w1  = (const float*)d_in[3];
    const float* b1  = (const float*)d_in[4];
    const float* w2  = (const float*)d_in[5];
    const float* b2  = (const float*)d_in[6];
    float* out = (float*)d_out;

    const size_t w1s_bytes = (size_t)JN * 16 * 1024 * 4 * 8 * sizeof(ushort_t); // 17825792

    if (ws_size >= w1s_bytes) {
        ushort_t* w1s = (ushort_t*)d_ws;
        prep_w1<<<JN * 16 * 4, 256, 0, stream>>>(w1, w1s);
        hipFuncSetAttribute((const void*)pjh_fused_v3,
                            hipFuncAttributeMaxDynamicSharedMemorySize, SMEM_V3);
        dim3 grid(MTOT / BM3, JN);   // 81 x 17
        pjh_fused_v3<<<grid, NTHR, SMEM_V3, stream>>>(x, ga, be, w1s, b1, w2, b2, out);
    } else {
        hipFuncSetAttribute((const void*)pjh_fused_v1,
                            hipFuncAttributeMaxDynamicSharedMemorySize, SMEM_V1);
        dim3 grid((MTOT + BM - 1) / BM, JN);
        pjh_fused_v1<<<grid, NTHR, SMEM_V1, stream>>>(x, ga, be, w1, b1, w2, b2, out);
    }
}